// Round 10
// baseline (192.289 us; speedup 1.0000x reference)
//
#include <hip/hip_runtime.h>
#include <stdint.h>

#define NEGV -1.0e9f
#define EPSV 1e-12f

typedef __attribute__((ext_vector_type(8))) short bf16x8;
typedef __attribute__((ext_vector_type(4))) float f32x4;

__device__ __forceinline__ unsigned int f2bf(float f) {
  unsigned int u = __builtin_bit_cast(unsigned int, f);
  u = u + 0x7FFFu + ((u >> 16) & 1u);   // round-to-nearest-even
  return u >> 16;
}

// RNE pack of two f32 -> packed bf16x2 in one VALU inst (same bits as f2bf pair;
// inputs are post-relu finite so NaN behavior is irrelevant).
__device__ __forceinline__ unsigned int cvt_pk_bf16(float lo, float hi) {
  unsigned int r;
  asm("v_cvt_pk_bf16_f32 %0, %1, %2" : "=v"(r) : "v"(lo), "v"(hi));
  return r;
}

// ---------------- k_prep: one launch, three independent jobs
__global__ __launch_bounds__(256) void k_prep(
    const float* __restrict__ state, const float* __restrict__ w1,
    const float* __restrict__ b1, const float* __restrict__ emb_w,
    const float* __restrict__ emb_b, const float* __restrict__ w2,
    float* __restrict__ W1e, float* __restrict__ sb,
    unsigned short* __restrict__ W2t) {
  const int blk = blockIdx.x;
  const int tid = threadIdx.x;
  if (blk < 4) {
    const int j = blk * 256 + tid;
    float a0 = 0.f, a1 = 0.f, a2 = 0.f, a3 = 0.f, a4 = 0.f;
    for (int e = 0; e < 256; ++e) {
      const float w = w1[(size_t)(512 + e) * 1024 + j];
      a0 += emb_w[0 * 256 + e] * w;
      a1 += emb_w[1 * 256 + e] * w;
      a2 += emb_w[2 * 256 + e] * w;
      a3 += emb_w[3 * 256 + e] * w;
      a4 += emb_w[4 * 256 + e] * w;
    }
    W1e[0 * 1024 + j] = a0;
    W1e[1 * 1024 + j] = a1;
    W1e[2 * 1024 + j] = a2;
    W1e[3 * 1024 + j] = a3;
    W1e[4 * 1024 + j] = a4;
  } else if (blk < 516) {
    const int blk2 = blk - 4;
    const int b = blk2 >> 2;
    const int j = (blk2 & 3) * 256 + tid;
    float acc = b1[j];
    for (int e = 0; e < 256; ++e)
      acc += emb_b[e] * w1[(size_t)(512 + e) * 1024 + j];
    const float* st = state + (size_t)b * 512;
    for (int s = 0; s < 512; ++s) acc += st[s] * w1[(size_t)s * 1024 + j];
    sb[(size_t)b * 1024 + j] = acc;
  } else {
    __shared__ float tile[64][65];
    const int blk2 = blk - 516;
    const int gn = blk2 & 15, gk = blk2 >> 4;
    const int c = tid & 63, w = tid >> 6;
#pragma unroll
    for (int i = 0; i < 16; ++i) {
      const int r = i * 4 + w;
      tile[r][c] = w2[(size_t)(gk * 64 + r) * 1024 + gn * 64 + c];
    }
    __syncthreads();
#pragma unroll
    for (int i = 0; i < 16; ++i) {
      const int r = i * 4 + w;
      W2t[(size_t)(gn * 64 + r) * 1024 + gk * 64 + c] = (unsigned short)f2bf(tile[c][r]);
    }
  }
}

// ---------------- k_h1: materialize H1 = relu(tf @ W1e + sb) as bf16 [65536][1024].
// 8 rows per thread (W1e regs amortized 8x); writes coalesced 16B.
__global__ __launch_bounds__(256) void k_h1(
    const float* __restrict__ tf, const float* __restrict__ sbm,
    const float* __restrict__ W1em, unsigned short* __restrict__ H1) {
  const int tid = threadIdx.x;
  const int j0 = (tid & 127) << 3;
  const int r0 = (blockIdx.x * 2 + (tid >> 7)) * 8;   // 8 rows per thread
  const int b = r0 >> 9;
  const float* sbp = sbm + (size_t)b * 1024 + j0;
  const float4 sa = *(const float4*)(sbp);
  const float4 sbv = *(const float4*)(sbp + 4);
  float4 wa[5], wb[5];
#pragma unroll
  for (int i = 0; i < 5; ++i) {
    wa[i] = *(const float4*)(W1em + i * 1024 + j0);
    wb[i] = *(const float4*)(W1em + i * 1024 + j0 + 4);
  }
#pragma unroll
  for (int r = 0; r < 8; ++r) {
    const float* f = tf + (size_t)(r0 + r) * 5;
    const float f0 = f[0], f1 = f[1], f2 = f[2], f3 = f[3], f4 = f[4];
    float h0 = fmaf(f4, wa[4].x, fmaf(f3, wa[3].x, fmaf(f2, wa[2].x, fmaf(f1, wa[1].x, fmaf(f0, wa[0].x, sa.x)))));
    float h1 = fmaf(f4, wa[4].y, fmaf(f3, wa[3].y, fmaf(f2, wa[2].y, fmaf(f1, wa[1].y, fmaf(f0, wa[0].y, sa.y)))));
    float h2 = fmaf(f4, wa[4].z, fmaf(f3, wa[3].z, fmaf(f2, wa[2].z, fmaf(f1, wa[1].z, fmaf(f0, wa[0].z, sa.z)))));
    float h3 = fmaf(f4, wa[4].w, fmaf(f3, wa[3].w, fmaf(f2, wa[2].w, fmaf(f1, wa[1].w, fmaf(f0, wa[0].w, sa.w)))));
    float h4 = fmaf(f4, wb[4].x, fmaf(f3, wb[3].x, fmaf(f2, wb[2].x, fmaf(f1, wb[1].x, fmaf(f0, wb[0].x, sbv.x)))));
    float h5 = fmaf(f4, wb[4].y, fmaf(f3, wb[3].y, fmaf(f2, wb[2].y, fmaf(f1, wb[1].y, fmaf(f0, wb[0].y, sbv.y)))));
    float h6 = fmaf(f4, wb[4].z, fmaf(f3, wb[3].z, fmaf(f2, wb[2].z, fmaf(f1, wb[1].z, fmaf(f0, wb[0].z, sbv.z)))));
    float h7 = fmaf(f4, wb[4].w, fmaf(f3, wb[3].w, fmaf(f2, wb[2].w, fmaf(f1, wb[1].w, fmaf(f0, wb[0].w, sbv.w)))));
    h0 = fmaxf(h0, 0.f); h1 = fmaxf(h1, 0.f); h2 = fmaxf(h2, 0.f); h3 = fmaxf(h3, 0.f);
    h4 = fmaxf(h4, 0.f); h5 = fmaxf(h5, 0.f); h6 = fmaxf(h6, 0.f); h7 = fmaxf(h7, 0.f);
    uint4 pk;
    pk.x = cvt_pk_bf16(h0, h1);
    pk.y = cvt_pk_bf16(h2, h3);
    pk.z = cvt_pk_bf16(h4, h5);
    pk.w = cvt_pk_bf16(h6, h7);
    *(uint4*)&H1[(size_t)(r0 + r) * 1024 + j0] = pk;
  }
}

// ---------------- k_gemm2: 8-wave 256x256 GEMM (H1 @ W2t), half-tile counted-vmcnt
// pipeline (T4, the m218-isolated lever: counted-vs-drain0 = +38-73%).
// R20: R8/R9 both drained vmcnt(0) per tile (forced by 2-buffer granularity)
// and sat at 40% MfmaUtil = the documented drain0 plateau. Restructure:
//   LDS = 4 half-K buffers As[4]/Bs[4], each [256 rows][32 k] swizzled
//   (same 128 KB). While reading half h: h+1, h+2 in flight, h+3 issuing.
//   Per thread 4 loads/half (2A+2B) -> boundary waits are vmcnt(8): only the
//   oldest 4 loads (issued ~4 phases earlier) must have landed. Never 0 in
//   steady state; exact tail waits vmcnt(8)/(4)/(0).
// Phase (m201-exact): { ds_reads (4 A; +4 B at half start); 1 STAGEH (2
//   loads); s_barrier; lgkmcnt(0)  [drains reads before post-barrier ->
//   buffer-reuse safe]; setprio(1); 16 MFMA; setprio(0); [boundary vmcnt];
//   s_barrier }. 4 phases/tile, K=32 per MFMA per half.
// Swizzle (R3-verified 0-conflict family): consumer chunk = lg ^ ((lm>>1)&3);
//   stage source chunk = (lane&3) ^ ((lane>>3)&3). Consistency: stage lane l
//   covers row r with (r>>1)&3 = (l>>3)&3, so slot (l&3) holds chunk
//   (l&3)^swz(r) and the consumer's p = c ^ swz(r) reads back chunk c.
__global__ __launch_bounds__(512, 2) void k_gemm2(
    const unsigned short* __restrict__ H1, const unsigned short* __restrict__ W2t,
    const float* __restrict__ b2, const float* __restrict__ w3,
    float* __restrict__ partial) {
  __shared__ unsigned short As[4][8192];   // [half-buf][256 rows][32 k] swizzled
  __shared__ unsigned short Bs[4][8192];   // [half-buf][256 cols][32 k] swizzled

  const int bid = blockIdx.x;
  const int swz = (bid & 7) * 128 + (bid >> 3);   // XCD swizzle (1024 % 8 == 0)
  const int bx = swz >> 2, by = swz & 3;
  const int row0 = bx << 8, col0 = by << 8;

  const int tid = threadIdx.x, lane = tid & 63, wid = tid >> 6;

  // ---- staging: per STAGEH call, each thread loads 16B of A and 16B of B.
  // load q covers rows/cols q*128..q*128+127: wave wid -> 16 rows, 4 lanes/row.
  const int rwrow = (wid << 4) + (lane >> 2);                 // wid*16 + lane/4
  const int srcsw = (((lane & 3) ^ ((lane >> 3) & 3)) << 3);  // pre-swizzled chunk
  const int ldstb = wid << 9;                                 // wave-uniform: wid*16 rows * 32

#define STAGEH(hh, q)                                                         \
    {                                                                         \
      __builtin_amdgcn_global_load_lds(                                       \
          (const __attribute__((address_space(1))) void*)(                    \
              H1 + (size_t)(row0 + (q) * 128 + rwrow) * 1024 + (hh) * 32 + srcsw), \
          (__attribute__((address_space(3))) void*)(                          \
              As[(hh) & 3] + (q) * 4096 + ldstb), 16, 0, 0);                  \
      __builtin_amdgcn_global_load_lds(                                       \
          (const __attribute__((address_space(1))) void*)(                    \
              W2t + (size_t)(col0 + (q) * 128 + rwrow) * 1024 + (hh) * 32 + srcsw), \
          (__attribute__((address_space(3))) void*)(                          \
              Bs[(hh) & 3] + (q) * 4096 + ldstb), 16, 0, 0);                  \
    }

  // ---- consumer constants (fragment geometry as before, 32-elem row stride)
  const int wr = wid >> 2, wc = wid & 3;
  const int lm = lane & 15, lg = lane >> 4;
  const int aoff = (wr * 128 + lm) * 32;        // + m*512 + s
  const int boff = (wc * 64 + lm) * 32;         // + n*512 + s
  const int s = ((lg ^ ((lm >> 1) & 3)) << 3);  // swizzled k-chunk

  f32x4 acc[8][4];
#pragma unroll
  for (int m = 0; m < 8; ++m)
#pragma unroll
    for (int n = 0; n < 4; ++n) acc[m][n] = (f32x4){0.f, 0.f, 0.f, 0.f};

  // ---- prologue: halves 0,1,2 in flight; wait half0 only (8 remain), converge
  STAGEH(0, 0); STAGEH(0, 1);
  STAGEH(1, 0); STAGEH(1, 1);
  STAGEH(2, 0); STAGEH(2, 1);
  asm volatile("s_waitcnt vmcnt(8)" ::: "memory");
  __builtin_amdgcn_s_barrier();

#pragma unroll 1
  for (int t = 0; t < 16; ++t) {
#pragma unroll
    for (int half = 0; half < 2; ++half) {
      const unsigned short* Ad = As[(2 * t + half) & 3];
      const unsigned short* Bd = Bs[(2 * t + half) & 3];
      bf16x8 bk[4];
#pragma unroll
      for (int n = 0; n < 4; ++n) bk[n] = *(const bf16x8*)(Bd + boff + n * 512 + s);
#pragma unroll
      for (int ph = 0; ph < 2; ++ph) {
        bf16x8 av[4];
#pragma unroll
        for (int i = 0; i < 4; ++i)
          av[i] = *(const bf16x8*)(Ad + aoff + (ph * 4 + i) * 512 + s);
        // stage: tile t issues halves 2t+3 (during half0) and 2t+4 (half1)
        const int hh = 2 * t + 3 + half;
        if (hh < 32) STAGEH(hh, ph);
        __builtin_amdgcn_s_barrier();
        asm volatile("s_waitcnt lgkmcnt(0)" ::: "memory");
        __builtin_amdgcn_s_setprio(1);
#pragma unroll
        for (int i = 0; i < 4; ++i)
#pragma unroll
          for (int n = 0; n < 4; ++n)
            acc[ph * 4 + i][n] = __builtin_amdgcn_mfma_f32_16x16x32_bf16(
                av[i], bk[n], acc[ph * 4 + i][n], 0, 0, 0);
        __builtin_amdgcn_s_setprio(0);
        // ---- half boundary: counted wait for the NEXT half's buffer.
        // FIFO per wave: 3 halves x 4 loads in flight -> wait to 8 drains
        // exactly the oldest half. Tail: h30 needs vmcnt(4), h31 vmcnt(0).
        if (ph == 1) {
          if (half == 0) {
            if (t < 15) { asm volatile("s_waitcnt vmcnt(8)" ::: "memory"); }
            else        { asm volatile("s_waitcnt vmcnt(0)" ::: "memory"); }
          } else {
            if (t < 14)       { asm volatile("s_waitcnt vmcnt(8)" ::: "memory"); }
            else if (t == 14) { asm volatile("s_waitcnt vmcnt(4)" ::: "memory"); }
            // t == 15: no further reads
          }
        }
        __builtin_amdgcn_s_barrier();
      }
    }
  }
#undef STAGEH

  // ---- epilogue: partial[row][by*4+wc] = sum_cols relu(acc + b2[col]) * w3[col]
  float b2v[4], w3v[4];
#pragma unroll
  for (int n = 0; n < 4; ++n) {
    const int col = col0 + wc * 64 + n * 16 + lm;
    b2v[n] = b2[col];
    w3v[n] = w3[col];
  }
#pragma unroll
  for (int m = 0; m < 8; ++m) {
#pragma unroll
    for (int r = 0; r < 4; ++r) {
      float v = 0.f;
#pragma unroll
      for (int n = 0; n < 4; ++n) {
        float h = acc[m][n][r] + b2v[n];
        h = fmaxf(h, 0.f);
        v += h * w3v[n];
      }
      v += __shfl_xor(v, 1, 16);
      v += __shfl_xor(v, 2, 16);
      v += __shfl_xor(v, 4, 16);
      v += __shfl_xor(v, 8, 16);
      if (lm == 0)
        partial[(size_t)(row0 + wr * 128 + m * 16 + lg * 4 + r) * 16 + by * 4 + wc] = v;
    }
  }
}

// ---------------- k_softmax: fused utils-reduction + nested-logit softmax
__global__ __launch_bounds__(256) void k_softmax(
    const float* __restrict__ partial, const float* __restrict__ b3,
    const int* __restrict__ nids, const int* __restrict__ mask,
    const float* __restrict__ etas, float* __restrict__ utils_out,
    float* __restrict__ p_task, float* __restrict__ p_nest) {
  const int b = blockIdx.x, tid = threadIdx.x;
  const int lane = tid & 63, wv = tid >> 6;
  __shared__ float smax[4][4];
  __shared__ int scnt[4][4];
  __shared__ float ssum[4][4];
  __shared__ float sred[4];
  __shared__ int sredi[4];

  const size_t base = (size_t)b * 512;
  const float b3v = b3[0];
  float uraw[2];
#pragma unroll
  for (int k = 0; k < 2; ++k) {
    const size_t row = base + tid + k * 256;
    const float4* p = (const float4*)(partial + row * 16);
    const float4 pa = p[0], pb = p[1], pc = p[2], pd = p[3];
    uraw[k] = b3v + pa.x + pa.y + pa.z + pa.w + pb.x + pb.y + pb.z + pb.w +
              pc.x + pc.y + pc.z + pc.w + pd.x + pd.y + pd.z + pd.w;
  }
  const int n0 = nids[base + tid], n1 = nids[base + 256 + tid];
  const bool m0 = mask[base + tid] != 0, m1 = mask[base + 256 + tid] != 0;
  const float u0 = m0 ? uraw[0] : NEGV;
  const float u1 = m1 ? uraw[1] : NEGV;
  utils_out[base + tid] = u0;
  utils_out[base + 256 + tid] = u1;
  const float eta[4] = {etas[0], etas[1], etas[2], etas[3]};

  float lmax[4]; int lcnt[4];
#pragma unroll
  for (int m = 0; m < 4; ++m) {
    const bool e0 = m0 && (n0 == m), e1 = m1 && (n1 == m);
    lmax[m] = fmaxf(e0 ? u0 : -INFINITY, e1 ? u1 : -INFINITY);
    lcnt[m] = (int)e0 + (int)e1;
  }
#pragma unroll
  for (int m = 0; m < 4; ++m)
#pragma unroll
    for (int off = 32; off >= 1; off >>= 1) {
      lmax[m] = fmaxf(lmax[m], __shfl_xor(lmax[m], off));
      lcnt[m] += __shfl_xor(lcnt[m], off);
    }
  if (lane == 0) {
#pragma unroll
    for (int m = 0; m < 4; ++m) { smax[wv][m] = lmax[m]; scnt[wv][m] = lcnt[m]; }
  }
  __syncthreads();
  float mval[4]; bool ne[4];
#pragma unroll
  for (int m = 0; m < 4; ++m) {
    const float mx = fmaxf(fmaxf(smax[0][m], smax[1][m]), fmaxf(smax[2][m], smax[3][m]));
    const int c = scnt[0][m] + scnt[1][m] + scnt[2][m] + scnt[3][m];
    ne[m] = c > 0;
    mval[m] = ne[m] ? mx : 0.f;
  }
  float lsum[4];
#pragma unroll
  for (int m = 0; m < 4; ++m) {
    float s = 0.f;
    if (m0 && n0 == m) s += expf((u0 - mval[m]) / eta[m]);
    if (m1 && n1 == m) s += expf((u1 - mval[m]) / eta[m]);
    lsum[m] = s;
  }
#pragma unroll
  for (int m = 0; m < 4; ++m)
#pragma unroll
    for (int off = 32; off >= 1; off >>= 1) lsum[m] += __shfl_xor(lsum[m], off);
  if (lane == 0) {
#pragma unroll
    for (int m = 0; m < 4; ++m) ssum[wv][m] = lsum[m];
  }
  __syncthreads();
  float sums[4], U[4];
#pragma unroll
  for (int m = 0; m < 4; ++m) {
    const float s = ssum[0][m] + ssum[1][m] + ssum[2][m] + ssum[3][m];
    sums[m] = fmaxf(s, EPSV);
    U[m] = ne[m] ? (mval[m] + eta[m] * logf(sums[m])) : NEGV;
  }
  const float mU = fmaxf(fmaxf(U[0], U[1]), fmaxf(U[2], U[3]));
  float pe[4], pes = 0.f;
#pragma unroll
  for (int m = 0; m < 4; ++m) { pe[m] = expf(U[m] - mU); pes += pe[m]; }
  float pn[4];
#pragma unroll
  for (int m = 0; m < 4; ++m) pn[m] = pe[m] / pes;
  if (tid == 0) {
#pragma unroll
    for (int m = 0; m < 4; ++m) p_nest[(size_t)b * 4 + m] = pn[m];
  }
  float pt[2];
  const float uu[2] = {u0, u1};
  const int nn[2] = {n0, n1};
  const bool mm[2] = {m0, m1};
#pragma unroll
  for (int k = 0; k < 2; ++k) {
    const bool valid = mm[k] && nn[k] >= 0 && nn[k] < 4;
    float mt = 0.f, st = 1.f, pnt = 0.f, et = 1.f;
#pragma unroll
    for (int m = 0; m < 4; ++m)
      if (nn[k] == m) { mt = mval[m]; st = sums[m]; pnt = pn[m]; et = eta[m]; }
    pt[k] = valid ? pnt * expf((uu[k] - mt) / et) / st : 0.f;
  }
  float lp = pt[0] + pt[1];
  int lmk = (int)m0 + (int)m1;
#pragma unroll
  for (int off = 32; off >= 1; off >>= 1) {
    lp += __shfl_xor(lp, off);
    lmk += __shfl_xor(lmk, off);
  }
  if (lane == 0) { sred[wv] = lp; sredi[wv] = lmk; }
  __syncthreads();
  const float sumpt = sred[0] + sred[1] + sred[2] + sred[3];
  const int nmask = sredi[0] + sredi[1] + sredi[2] + sredi[3];
  const bool fallback = (nmask > 0) && (sumpt <= EPSV);
  if (fallback) {
    const float uni = 1.f / (float)(nmask > 0 ? nmask : 1);
    pt[0] = m0 ? uni : pt[0];
    pt[1] = m1 ? uni : pt[1];
  }
  p_task[base + tid] = pt[0];
  p_task[base + 256 + tid] = pt[1];
}

extern "C" void kernel_launch(void* const* d_in, const int* in_sizes, int n_in,
                              void* d_out, int out_size, void* d_ws, size_t ws_size,
                              hipStream_t stream) {
  const float* state = (const float*)d_in[0];
  const float* tf = (const float*)d_in[1];
  const int* nids = (const int*)d_in[2];
  const int* mask = (const int*)d_in[3];
  const float* emb_w = (const float*)d_in[4];
  const float* emb_b = (const float*)d_in[5];
  const float* w1 = (const float*)d_in[6];
  const float* b1 = (const float*)d_in[7];
  const float* w2 = (const float*)d_in[8];
  const float* b2 = (const float*)d_in[9];
  const float* w3 = (const float*)d_in[10];
  const float* b3 = (const float*)d_in[11];
  const float* etas = (const float*)d_in[12];

  float* out = (float*)d_out;
  float* utils_out = out;            // 65536
  float* p_task = out + 65536;       // 65536
  float* p_nest = out + 131072;      // 512

  char* ws = (char*)d_ws;
  unsigned short* W2t = (unsigned short*)ws; ws += 1024ull * 1024 * 2;    // 2 MB
  float* partial = (float*)ws;               ws += 65536ull * 16 * 4;     // 4 MB
  float* W1e = (float*)ws;                   ws += 5 * 1024 * 4;
  float* sb = (float*)ws;                    ws += 128 * 1024 * 4;
  unsigned short* H1 = (unsigned short*)ws;  ws += 65536ull * 1024 * 2;   // 128 MB

  k_prep<<<772, 256, 0, stream>>>(state, w1, b1, emb_w, emb_b, w2, W1e, sb, W2t);
  k_h1<<<4096, 256, 0, stream>>>(tf, sb, W1e, H1);
  k_gemm2<<<1024, 512, 0, stream>>>(H1, W2t, b2, w3, partial);
  k_softmax<<<128, 256, 0, stream>>>(partial, b3, nids, mask, etas,
                                     utils_out, p_task, p_nest);
}

// Round 11
// 181.730 us; speedup vs baseline: 1.0581x; 1.0581x over previous
//
#include <hip/hip_runtime.h>
#include <stdint.h>

#define NEGV -1.0e9f
#define EPSV 1e-12f

typedef __attribute__((ext_vector_type(8))) short bf16x8;
typedef __attribute__((ext_vector_type(4))) float f32x4;

__device__ __forceinline__ unsigned int f2bf(float f) {
  unsigned int u = __builtin_bit_cast(unsigned int, f);
  u = u + 0x7FFFu + ((u >> 16) & 1u);   // round-to-nearest-even
  return u >> 16;
}

// RNE pack of two f32 -> packed bf16x2 in one VALU inst (same bits as f2bf pair;
// inputs are post-relu finite so NaN behavior is irrelevant).
__device__ __forceinline__ unsigned int cvt_pk_bf16(float lo, float hi) {
  unsigned int r;
  asm("v_cvt_pk_bf16_f32 %0, %1, %2" : "=v"(r) : "v"(lo), "v"(hi));
  return r;
}

// ---------------- k_prep: one launch, three independent jobs
__global__ __launch_bounds__(256) void k_prep(
    const float* __restrict__ state, const float* __restrict__ w1,
    const float* __restrict__ b1, const float* __restrict__ emb_w,
    const float* __restrict__ emb_b, const float* __restrict__ w2,
    float* __restrict__ W1e, float* __restrict__ sb,
    unsigned short* __restrict__ W2t) {
  const int blk = blockIdx.x;
  const int tid = threadIdx.x;
  if (blk < 4) {
    const int j = blk * 256 + tid;
    float a0 = 0.f, a1 = 0.f, a2 = 0.f, a3 = 0.f, a4 = 0.f;
    for (int e = 0; e < 256; ++e) {
      const float w = w1[(size_t)(512 + e) * 1024 + j];
      a0 += emb_w[0 * 256 + e] * w;
      a1 += emb_w[1 * 256 + e] * w;
      a2 += emb_w[2 * 256 + e] * w;
      a3 += emb_w[3 * 256 + e] * w;
      a4 += emb_w[4 * 256 + e] * w;
    }
    W1e[0 * 1024 + j] = a0;
    W1e[1 * 1024 + j] = a1;
    W1e[2 * 1024 + j] = a2;
    W1e[3 * 1024 + j] = a3;
    W1e[4 * 1024 + j] = a4;
  } else if (blk < 516) {
    const int blk2 = blk - 4;
    const int b = blk2 >> 2;
    const int j = (blk2 & 3) * 256 + tid;
    float acc = b1[j];
    for (int e = 0; e < 256; ++e)
      acc += emb_b[e] * w1[(size_t)(512 + e) * 1024 + j];
    const float* st = state + (size_t)b * 512;
    for (int s = 0; s < 512; ++s) acc += st[s] * w1[(size_t)s * 1024 + j];
    sb[(size_t)b * 1024 + j] = acc;
  } else {
    __shared__ float tile[64][65];
    const int blk2 = blk - 516;
    const int gn = blk2 & 15, gk = blk2 >> 4;
    const int c = tid & 63, w = tid >> 6;
#pragma unroll
    for (int i = 0; i < 16; ++i) {
      const int r = i * 4 + w;
      tile[r][c] = w2[(size_t)(gk * 64 + r) * 1024 + gn * 64 + c];
    }
    __syncthreads();
#pragma unroll
    for (int i = 0; i < 16; ++i) {
      const int r = i * 4 + w;
      W2t[(size_t)(gn * 64 + r) * 1024 + gk * 64 + c] = (unsigned short)f2bf(tile[c][r]);
    }
  }
}

// ---------------- k_h1: materialize H1 = relu(tf @ W1e + sb) as bf16 [65536][1024].
// 8 rows per thread (W1e regs amortized 8x); writes coalesced 16B.
// R21: preload ALL 8 rows' tf (40 regs) before the compute loop — the store
// stream then runs without interleaved scattered-load stalls (store-bound
// kernel at ~73% of write roofline; the tf loads were the latency gaps).
__global__ __launch_bounds__(256) void k_h1(
    const float* __restrict__ tf, const float* __restrict__ sbm,
    const float* __restrict__ W1em, unsigned short* __restrict__ H1) {
  const int tid = threadIdx.x;
  const int j0 = (tid & 127) << 3;
  const int r0 = (blockIdx.x * 2 + (tid >> 7)) * 8;   // 8 rows per thread
  const int b = r0 >> 9;
  // ---- preload tf rows first (independent scattered loads, issued together)
  float ptf[8][5];
#pragma unroll
  for (int r = 0; r < 8; ++r) {
    const float* f = tf + (size_t)(r0 + r) * 5;
#pragma unroll
    for (int i = 0; i < 5; ++i) ptf[r][i] = f[i];
  }
  const float* sbp = sbm + (size_t)b * 1024 + j0;
  const float4 sa = *(const float4*)(sbp);
  const float4 sbv = *(const float4*)(sbp + 4);
  float4 wa[5], wb[5];
#pragma unroll
  for (int i = 0; i < 5; ++i) {
    wa[i] = *(const float4*)(W1em + i * 1024 + j0);
    wb[i] = *(const float4*)(W1em + i * 1024 + j0 + 4);
  }
#pragma unroll
  for (int r = 0; r < 8; ++r) {
    const float f0 = ptf[r][0], f1 = ptf[r][1], f2 = ptf[r][2],
                f3 = ptf[r][3], f4 = ptf[r][4];
    float h0 = fmaf(f4, wa[4].x, fmaf(f3, wa[3].x, fmaf(f2, wa[2].x, fmaf(f1, wa[1].x, fmaf(f0, wa[0].x, sa.x)))));
    float h1 = fmaf(f4, wa[4].y, fmaf(f3, wa[3].y, fmaf(f2, wa[2].y, fmaf(f1, wa[1].y, fmaf(f0, wa[0].y, sa.y)))));
    float h2 = fmaf(f4, wa[4].z, fmaf(f3, wa[3].z, fmaf(f2, wa[2].z, fmaf(f1, wa[1].z, fmaf(f0, wa[0].z, sa.z)))));
    float h3 = fmaf(f4, wa[4].w, fmaf(f3, wa[3].w, fmaf(f2, wa[2].w, fmaf(f1, wa[1].w, fmaf(f0, wa[0].w, sa.w)))));
    float h4 = fmaf(f4, wb[4].x, fmaf(f3, wb[3].x, fmaf(f2, wb[2].x, fmaf(f1, wb[1].x, fmaf(f0, wb[0].x, sbv.x)))));
    float h5 = fmaf(f4, wb[4].y, fmaf(f3, wb[3].y, fmaf(f2, wb[2].y, fmaf(f1, wb[1].y, fmaf(f0, wb[0].y, sbv.y)))));
    float h6 = fmaf(f4, wb[4].z, fmaf(f3, wb[3].z, fmaf(f2, wb[2].z, fmaf(f1, wb[1].z, fmaf(f0, wb[0].z, sbv.z)))));
    float h7 = fmaf(f4, wb[4].w, fmaf(f3, wb[3].w, fmaf(f2, wb[2].w, fmaf(f1, wb[1].w, fmaf(f0, wb[0].w, sbv.w)))));
    h0 = fmaxf(h0, 0.f); h1 = fmaxf(h1, 0.f); h2 = fmaxf(h2, 0.f); h3 = fmaxf(h3, 0.f);
    h4 = fmaxf(h4, 0.f); h5 = fmaxf(h5, 0.f); h6 = fmaxf(h6, 0.f); h7 = fmaxf(h7, 0.f);
    uint4 pk;
    pk.x = cvt_pk_bf16(h0, h1);
    pk.y = cvt_pk_bf16(h2, h3);
    pk.z = cvt_pk_bf16(h4, h5);
    pk.w = cvt_pk_bf16(h6, h7);
    *(uint4*)&H1[(size_t)(r0 + r) * 1024 + j0] = pk;
  }
}

// ---------------- k_gemm2: 8-wave 256x256 GEMM (H1 @ W2t) — R9 VERBATIM.
// R21 decision: five schedule structures (R7-R10) all land 37-40% MfmaUtil /
// 143-157us — the LDS-read pipe (~2300 cyc/tile, CU-shared) and MFMA pipe
// (~2486 cyc/SIMD) are additive in every barrier/waitcnt topology expressible
// here (R10's counted-vmcnt even regressed). R9 = measured optimum of the
// family; frozen. Remaining headroom is the HK-exact combo (not
// reconstructable blind; m152: naive combination underperforms).
__global__ __launch_bounds__(512, 2) void k_gemm2(
    const unsigned short* __restrict__ H1, const unsigned short* __restrict__ W2t,
    const float* __restrict__ b2, const float* __restrict__ w3,
    float* __restrict__ partial) {
  __shared__ unsigned short As[2][16384];   // [buf][256 rows][64 k] swizzled
  __shared__ unsigned short Bs[2][16384];

  const int bid = blockIdx.x;
  const int swz = (bid & 7) * 128 + (bid >> 3);   // XCD swizzle (1024 % 8 == 0)
  const int bx = swz >> 2, by = swz & 3;
  const int row0 = bx << 8, col0 = by << 8;

  const int tid = threadIdx.x, lane = tid & 63, wid = tid >> 6;

  // ---- staging addresses (all 8 waves stage both A and B)
  const int sr = (wid << 5) + (lane >> 3);               // tile row; + q*8
  const int scol = (((lane & 7) ^ ((lane >> 3) & 7)) << 3);  // pre-swizzled src chunk
  const size_t abase = (size_t)(row0 + sr) * 1024 + scol;
  const size_t bbase = (size_t)(col0 + sr) * 1024 + scol;
  const int ldsb = (wid << 5) * 64;                      // wave-uniform dest; + q*512

#define STAGE8(kt, d)                                                         \
    _Pragma("unroll")                                                         \
    for (int q = 0; q < 4; ++q) {                                             \
      __builtin_amdgcn_global_load_lds(                                       \
          (const __attribute__((address_space(1))) void*)(                    \
              H1 + abase + (size_t)q * 8192 + (kt) * 64),                     \
          (__attribute__((address_space(3))) void*)(As[d] + ldsb + q * 512),  \
          16, 0, 0);                                                          \
      __builtin_amdgcn_global_load_lds(                                       \
          (const __attribute__((address_space(1))) void*)(                    \
              W2t + bbase + (size_t)q * 8192 + (kt) * 64),                    \
          (__attribute__((address_space(3))) void*)(Bs[d] + ldsb + q * 512),  \
          16, 0, 0);                                                          \
    }

  // 4 loads: q-pairs {2g, 2g+1} of (A,B)
#define STAGE4(kt, d, g)                                                      \
    _Pragma("unroll")                                                         \
    for (int qq = 2 * (g); qq < 2 * (g) + 2; ++qq) {                          \
      __builtin_amdgcn_global_load_lds(                                       \
          (const __attribute__((address_space(1))) void*)(                    \
              H1 + abase + (size_t)qq * 8192 + (kt) * 64),                    \
          (__attribute__((address_space(3))) void*)(As[d] + ldsb + qq * 512), \
          16, 0, 0);                                                          \
      __builtin_amdgcn_global_load_lds(                                       \
          (const __attribute__((address_space(1))) void*)(                    \
              W2t + bbase + (size_t)qq * 8192 + (kt) * 64),                   \
          (__attribute__((address_space(3))) void*)(Bs[d] + ldsb + qq * 512), \
          16, 0, 0);                                                          \
    }

  // ---- consumer-side constants
  const int wr = wid >> 2, wc = wid & 3;
  const int lm = lane & 15, lg = lane >> 4;
  const int aoff = (wr * 128 + lm) * 64;        // + m*1024 + s{0,1}
  const int boff = (wc * 64 + lm) * 64;         // + n*1024 + s{0,1}
  const int s0 = ((lg ^ (lm & 7)) << 3);        // k16 = lg
  const int s1 = (((4 + lg) ^ (lm & 7)) << 3);  // k16 = 4+lg

  f32x4 acc[8][4];
#pragma unroll
  for (int m = 0; m < 8; ++m)
#pragma unroll
    for (int n = 0; n < 4; ++n) acc[m][n] = (f32x4){0.f, 0.f, 0.f, 0.f};

  // ---- prologue: stage tile 0, full drain
  STAGE8(0, 0);
  __syncthreads();

#pragma unroll 1
  for (int t = 0; t < 16; ++t) {
    const unsigned short* Ad = As[t & 1];
    const unsigned short* Bd = Bs[t & 1];
    bf16x8 bk0[4], bk1[4], aS[2][4];
    // ---- tile-top burst: all 8 B-frags + phase-0 A-frags
#pragma unroll
    for (int n = 0; n < 4; ++n) {
      bk0[n] = *(const bf16x8*)(Bd + boff + n * 1024 + s0);
      bk1[n] = *(const bf16x8*)(Bd + boff + n * 1024 + s1);
    }
    aS[0][0] = *(const bf16x8*)(Ad + aoff + 0 * 1024 + s0);
    aS[0][1] = *(const bf16x8*)(Ad + aoff + 0 * 1024 + s1);
    aS[0][2] = *(const bf16x8*)(Ad + aoff + 1 * 1024 + s0);
    aS[0][3] = *(const bf16x8*)(Ad + aoff + 1 * 1024 + s1);
#pragma unroll
    for (int p = 0; p < 4; ++p) {
      const int cur = p & 1, nxt = cur ^ 1;
      // ---- next phase's A-frags (one phase ahead; compiler emits the
      //      fine-grained lgkm waits at their first MFMA use next phase)
      if (p < 3) {
        aS[nxt][0] = *(const bf16x8*)(Ad + aoff + (2 * p + 2) * 1024 + s0);
        aS[nxt][1] = *(const bf16x8*)(Ad + aoff + (2 * p + 2) * 1024 + s1);
        aS[nxt][2] = *(const bf16x8*)(Ad + aoff + (2 * p + 3) * 1024 + s0);
        aS[nxt][3] = *(const bf16x8*)(Ad + aoff + (2 * p + 3) * 1024 + s1);
      }
      // ---- staging early: 4 loads at p0, 4 at p1 (drain slack >=2 phases)
      if (t < 15 && p < 2) STAGE4(t + 1, (t + 1) & 1, p);
      __builtin_amdgcn_s_barrier();
      __builtin_amdgcn_s_setprio(1);
#pragma unroll
      for (int n = 0; n < 4; ++n)
        acc[2 * p][n] = __builtin_amdgcn_mfma_f32_16x16x32_bf16(aS[cur][0], bk0[n], acc[2 * p][n], 0, 0, 0);
#pragma unroll
      for (int n = 0; n < 4; ++n)
        acc[2 * p][n] = __builtin_amdgcn_mfma_f32_16x16x32_bf16(aS[cur][1], bk1[n], acc[2 * p][n], 0, 0, 0);
#pragma unroll
      for (int n = 0; n < 4; ++n)
        acc[2 * p + 1][n] = __builtin_amdgcn_mfma_f32_16x16x32_bf16(aS[cur][2], bk0[n], acc[2 * p + 1][n], 0, 0, 0);
#pragma unroll
      for (int n = 0; n < 4; ++n)
        acc[2 * p + 1][n] = __builtin_amdgcn_mfma_f32_16x16x32_bf16(aS[cur][3], bk1[n], acc[2 * p + 1][n], 0, 0, 0);
      __builtin_amdgcn_s_setprio(0);
      // ---- tile end: drain own 8 stage loads (issued at p0/p1)
      if (p == 3 && t < 15) asm volatile("s_waitcnt vmcnt(0)" ::: "memory");
      __builtin_amdgcn_s_barrier();
    }
  }
#undef STAGE8
#undef STAGE4

  // ---- epilogue: partial[row][by*4+wc] = sum_cols relu(acc + b2[col]) * w3[col]
  float b2v[4], w3v[4];
#pragma unroll
  for (int n = 0; n < 4; ++n) {
    const int col = col0 + wc * 64 + n * 16 + lm;
    b2v[n] = b2[col];
    w3v[n] = w3[col];
  }
#pragma unroll
  for (int m = 0; m < 8; ++m) {
#pragma unroll
    for (int r = 0; r < 4; ++r) {
      float v = 0.f;
#pragma unroll
      for (int n = 0; n < 4; ++n) {
        float h = acc[m][n][r] + b2v[n];
        h = fmaxf(h, 0.f);
        v += h * w3v[n];
      }
      v += __shfl_xor(v, 1, 16);
      v += __shfl_xor(v, 2, 16);
      v += __shfl_xor(v, 4, 16);
      v += __shfl_xor(v, 8, 16);
      if (lm == 0)
        partial[(size_t)(row0 + wr * 128 + m * 16 + lg * 4 + r) * 16 + by * 4 + wc] = v;
    }
  }
}

// ---------------- k_softmax: fused utils-reduction + nested-logit softmax
// R21: 512 threads, 1 task/thread (was 2) — halves serial work and shuffle
// depth in a latency-bound kernel. 8 waves/block, cross-wave via LDS.
__global__ __launch_bounds__(512) void k_softmax(
    const float* __restrict__ partial, const float* __restrict__ b3,
    const int* __restrict__ nids, const int* __restrict__ mask,
    const float* __restrict__ etas, float* __restrict__ utils_out,
    float* __restrict__ p_task, float* __restrict__ p_nest) {
  const int b = blockIdx.x, tid = threadIdx.x;
  const int lane = tid & 63, wv = tid >> 6;
  __shared__ float smax[8][4];
  __shared__ int scnt[8][4];
  __shared__ float ssum[8][4];
  __shared__ float sred[8];
  __shared__ int sredi[8];

  const size_t base = (size_t)b * 512;
  const float b3v = b3[0];
  const size_t row = base + tid;
  const float4* p = (const float4*)(partial + row * 16);
  const float4 pa = p[0], pb = p[1], pc = p[2], pd = p[3];
  const float uraw = b3v + pa.x + pa.y + pa.z + pa.w + pb.x + pb.y + pb.z + pb.w +
                     pc.x + pc.y + pc.z + pc.w + pd.x + pd.y + pd.z + pd.w;
  const int n0 = nids[row];
  const bool m0 = mask[row] != 0;
  const float u0 = m0 ? uraw : NEGV;
  utils_out[row] = u0;
  const float eta[4] = {etas[0], etas[1], etas[2], etas[3]};

  float lmax[4]; int lcnt[4];
#pragma unroll
  for (int m = 0; m < 4; ++m) {
    const bool e0 = m0 && (n0 == m);
    lmax[m] = e0 ? u0 : -INFINITY;
    lcnt[m] = (int)e0;
  }
#pragma unroll
  for (int m = 0; m < 4; ++m)
#pragma unroll
    for (int off = 32; off >= 1; off >>= 1) {
      lmax[m] = fmaxf(lmax[m], __shfl_xor(lmax[m], off));
      lcnt[m] += __shfl_xor(lcnt[m], off);
    }
  if (lane == 0) {
#pragma unroll
    for (int m = 0; m < 4; ++m) { smax[wv][m] = lmax[m]; scnt[wv][m] = lcnt[m]; }
  }
  __syncthreads();
  float mval[4]; bool ne[4];
#pragma unroll
  for (int m = 0; m < 4; ++m) {
    float mx = smax[0][m];
    int c = scnt[0][m];
#pragma unroll
    for (int w = 1; w < 8; ++w) { mx = fmaxf(mx, smax[w][m]); c += scnt[w][m]; }
    ne[m] = c > 0;
    mval[m] = ne[m] ? mx : 0.f;
  }
  float lsum[4];
#pragma unroll
  for (int m = 0; m < 4; ++m)
    lsum[m] = (m0 && n0 == m) ? expf((u0 - mval[m]) / eta[m]) : 0.f;
#pragma unroll
  for (int m = 0; m < 4; ++m)
#pragma unroll
    for (int off = 32; off >= 1; off >>= 1) lsum[m] += __shfl_xor(lsum[m], off);
  if (lane == 0) {
#pragma unroll
    for (int m = 0; m < 4; ++m) ssum[wv][m] = lsum[m];
  }
  __syncthreads();
  float sums[4], U[4];
#pragma unroll
  for (int m = 0; m < 4; ++m) {
    float s = ssum[0][m];
#pragma unroll
    for (int w = 1; w < 8; ++w) s += ssum[w][m];
    sums[m] = fmaxf(s, EPSV);
    U[m] = ne[m] ? (mval[m] + eta[m] * logf(sums[m])) : NEGV;
  }
  const float mU = fmaxf(fmaxf(U[0], U[1]), fmaxf(U[2], U[3]));
  float pe[4], pes = 0.f;
#pragma unroll
  for (int m = 0; m < 4; ++m) { pe[m] = expf(U[m] - mU); pes += pe[m]; }
  float pn[4];
#pragma unroll
  for (int m = 0; m < 4; ++m) pn[m] = pe[m] / pes;
  if (tid == 0) {
#pragma unroll
    for (int m = 0; m < 4; ++m) p_nest[(size_t)b * 4 + m] = pn[m];
  }
  const bool valid = m0 && n0 >= 0 && n0 < 4;
  float mt = 0.f, st = 1.f, pnt = 0.f, et = 1.f;
#pragma unroll
  for (int m = 0; m < 4; ++m)
    if (n0 == m) { mt = mval[m]; st = sums[m]; pnt = pn[m]; et = eta[m]; }
  float pt = valid ? pnt * expf((u0 - mt) / et) / st : 0.f;

  float lp = pt;
  int lmk = (int)m0;
#pragma unroll
  for (int off = 32; off >= 1; off >>= 1) {
    lp += __shfl_xor(lp, off);
    lmk += __shfl_xor(lmk, off);
  }
  if (lane == 0) { sred[wv] = lp; sredi[wv] = lmk; }
  __syncthreads();
  float sumpt = sred[0];
  int nmask = sredi[0];
#pragma unroll
  for (int w = 1; w < 8; ++w) { sumpt += sred[w]; nmask += sredi[w]; }
  const bool fallback = (nmask > 0) && (sumpt <= EPSV);
  if (fallback) {
    const float uni = 1.f / (float)(nmask > 0 ? nmask : 1);
    pt = m0 ? uni : pt;
  }
  p_task[row] = pt;
}

extern "C" void kernel_launch(void* const* d_in, const int* in_sizes, int n_in,
                              void* d_out, int out_size, void* d_ws, size_t ws_size,
                              hipStream_t stream) {
  const float* state = (const float*)d_in[0];
  const float* tf = (const float*)d_in[1];
  const int* nids = (const int*)d_in[2];
  const int* mask = (const int*)d_in[3];
  const float* emb_w = (const float*)d_in[4];
  const float* emb_b = (const float*)d_in[5];
  const float* w1 = (const float*)d_in[6];
  const float* b1 = (const float*)d_in[7];
  const float* w2 = (const float*)d_in[8];
  const float* b2 = (const float*)d_in[9];
  const float* w3 = (const float*)d_in[10];
  const float* b3 = (const float*)d_in[11];
  const float* etas = (const float*)d_in[12];

  float* out = (float*)d_out;
  float* utils_out = out;            // 65536
  float* p_task = out + 65536;       // 65536
  float* p_nest = out + 131072;      // 512

  char* ws = (char*)d_ws;
  unsigned short* W2t = (unsigned short*)ws; ws += 1024ull * 1024 * 2;    // 2 MB
  float* partial = (float*)ws;               ws += 65536ull * 16 * 4;     // 4 MB
  float* W1e = (float*)ws;                   ws += 5 * 1024 * 4;
  float* sb = (float*)ws;                    ws += 128 * 1024 * 4;
  unsigned short* H1 = (unsigned short*)ws;  ws += 65536ull * 1024 * 2;   // 128 MB

  k_prep<<<772, 256, 0, stream>>>(state, w1, b1, emb_w, emb_b, w2, W1e, sb, W2t);
  k_h1<<<4096, 256, 0, stream>>>(tf, sb, W1e, H1);
  k_gemm2<<<1024, 512, 0, stream>>>(H1, W2t, b2, w3, partial);
  k_softmax<<<128, 512, 0, stream>>>(partial, b3, nids, mask, etas,
                                     utils_out, p_task, p_nest);
}